// Round 15
// baseline (254.589 us; speedup 1.0000x reference)
//
#include <hip/hip_runtime.h>
#include <hip/hip_bf16.h>
#include <stdint.h>

// ---- problem constants ----
#define D_MODEL 1024
#define SEQ     2048
#define BATCH   4
#define NHEAD   16
#define DKH     64
#define MTOT    (BATCH * SEQ)      // 8192

typedef __bf16 bf16x8 __attribute__((ext_vector_type(8)));
typedef __bf16 bf16x4 __attribute__((ext_vector_type(4)));
typedef float  floatx4 __attribute__((ext_vector_type(4)));
typedef short  s16x4  __attribute__((ext_vector_type(4)));

#define GLOAD_LDS16(gp, lp)                                            \
    __builtin_amdgcn_global_load_lds(                                  \
        (const __attribute__((address_space(1))) unsigned int*)(gp),   \
        (__attribute__((address_space(3))) unsigned int*)(lp), 16, 0, 0)

#define MFMA16(a, b, c) __builtin_amdgcn_mfma_f32_16x16x32_bf16(a, b, c, 0, 0, 0)

#if __has_builtin(__builtin_amdgcn_exp2f)
#define EXP2(x) __builtin_amdgcn_exp2f(x)
#else
#define EXP2(x) exp2f(x)
#endif

// PV matmul: K=16 MFMA whose A-fragment layout (A[row=l&15][k=(l>>4)*4+i])
// exactly matches the QK^T output register layout (P[q=r16][k=quad*4+r]).
static __device__ __forceinline__ floatx4 pv_mfma(s16x4 a, s16x4 b, floatx4 c)
{
#if __has_builtin(__builtin_amdgcn_mfma_f32_16x16x16bf16_1k)
    return __builtin_amdgcn_mfma_f32_16x16x16bf16_1k(a, b, c, 0, 0, 0);
#else
    asm("v_mfma_f32_16x16x16_bf16 %0, %1, %2, %0" : "+v"(c) : "v"(a), "v"(b));
    return c;
#endif
}

// ---------------------------------------------------------------------------
// fp32 -> bf16: x / Wo (exact-size grid, no guard).
// ---------------------------------------------------------------------------
__global__ __launch_bounds__(256)
void cvt_x_kernel(const float* __restrict__ src, __bf16* __restrict__ dst)
{
    const int i = (blockIdx.x * 256 + threadIdx.x) * 4;
    floatx4 v = *(const floatx4*)(src + i);
    bf16x4 o;
    o[0] = (__bf16)v[0]; o[1] = (__bf16)v[1]; o[2] = (__bf16)v[2]; o[3] = (__bf16)v[3];
    *(bf16x4*)(dst + i) = o;
}

// fp32 -> bf16: Wq/Wk/Wv stacked into Wcat[3072,1024]. grid (1024, 3).
__global__ __launch_bounds__(256)
void cvt_w3_kernel(const float* __restrict__ Wq, const float* __restrict__ Wk,
                   const float* __restrict__ Wv, __bf16* __restrict__ Wcat)
{
    const int z = blockIdx.y;
    const float* src = (z == 0) ? Wq : ((z == 1) ? Wk : Wv);
    const int i = (blockIdx.x * 256 + threadIdx.x) * 4;
    floatx4 v = *(const floatx4*)(src + i);
    bf16x4 o;
    o[0] = (__bf16)v[0]; o[1] = (__bf16)v[1]; o[2] = (__bf16)v[2]; o[3] = (__bf16)v[3];
    *(bf16x4*)(Wcat + (size_t)z * (D_MODEL * D_MODEL) + i) = o;
}

// ---------------------------------------------------------------------------
// QKV GEMM — round-15: 256x128 tile, 512 threads (8 waves 4m x 2n),
// grid (24, 32) = 768 blocks.
// Tail arithmetic: per-wave state identical to the 128x128 version
// (acc[4][4], same frags; 3 staging ptrs) -> VGPR ~76-80 -> 6 waves/SIMD ->
// 3 blocks/CU x 8 waves; 768 = 3 x 256 EXACTLY -> zero scheduling tail
// (was 1536 blocks vs 4/CU = 1.5 rounds, the proven residual limit).
// 24 waves/CU (was 16). LDS: staging A 16KB + B 8KB; Cs epilogue overlay
// 34816B (proven full-width pattern, TWO m-half passes) -> union 34816.
// Default __launch_bounds__(512) — NO min-waves arg (round-10 lesson).
// z = n0>>10: 0->Q [b,h,s,d] (PRE-SCALED by log2e/8), 1->K, 2->V^T [b,h,d,s].
// ---------------------------------------------------------------------------
__global__ __launch_bounds__(512)
void qkv_gemm_kernel(const __bf16* __restrict__ xb, const __bf16* __restrict__ Wcat,
                     const float* __restrict__ bq, const float* __restrict__ bk,
                     const float* __restrict__ bv,
                     __bf16* __restrict__ Q, __bf16* __restrict__ K,
                     __bf16* __restrict__ Vt)
{
    // [As 16KB][Bs 8KB] staging  |  Cs[128][136] epilogue overlay (34816B)
    __shared__ __align__(16) char smem_raw[34816];
    __bf16* As = (__bf16*)smem_raw;
    __bf16* Bs = (__bf16*)(smem_raw + 16384);
    __bf16* Cs = (__bf16*)smem_raw;

    const int t    = threadIdx.x;                     // 0..511
    const int w    = t >> 6, l = t & 63, quad = l >> 4, r16 = l & 15;
    const int wm   = w >> 1, wn = w & 1;              // 4m x 2n wave grid
    const int m0   = blockIdx.y * 256;
    const int n0   = blockIdx.x * 128;
    const int z    = n0 >> 10;                        // block-uniform
    const float* bias = (z == 0) ? bq : ((z == 1) ? bk : bv);
    __bf16* outQK     = (z == 0) ? Q  : K;
    // fold 1/sqrt(64) * log2(e) into Q so attention can use raw v_exp_f32
    const float scale = (z == 0) ? 0.18033688011112042f : 1.0f;

    floatx4 acc[4][4];
#pragma unroll
    for (int i = 0; i < 4; ++i)
#pragma unroll
        for (int j = 0; j < 4; ++j) acc[i][j] = (floatx4){0.f, 0.f, 0.f, 0.f};

    // staging: A = 1024 chunks (2/thread), B = 512 chunks (1/thread).
    // source chunk pre-swizzled (sch = ch ^ (row&3)); LDS dest linear.
    const int cA0 = t, cA1 = t + 512, cB = t;
    const int rA0 = cA0 >> 2, sA0 = ((cA0 & 3) ^ (rA0 & 3)) * 8;
    const int rA1 = cA1 >> 2, sA1 = ((cA1 & 3) ^ (rA1 & 3)) * 8;
    const int rB  = cB >> 2,  sB  = ((cB & 3) ^ (rB & 3)) * 8;
    const __bf16* Ag0 = xb   + (size_t)(m0 + rA0) * 1024 + sA0;
    const __bf16* Ag1 = xb   + (size_t)(m0 + rA1) * 1024 + sA1;
    const __bf16* Bg  = Wcat + (size_t)(n0 + rB) * 1024 + sB;
    unsigned int* lAs = (unsigned int*)As;
    unsigned int* lBs = (unsigned int*)Bs;

    // fragment read swizzle: chunk' = quad ^ (r16&3)
    const int fsw = (quad ^ (r16 & 3)) * 8;

    for (int k0 = 0; k0 < 1024; k0 += 32) {
        __syncthreads();
        GLOAD_LDS16(Ag0 + k0, lAs + cA0 * 4);
        GLOAD_LDS16(Ag1 + k0, lAs + cA1 * 4);
        GLOAD_LDS16(Bg  + k0, lBs + cB * 4);
        __syncthreads();

        bf16x8 af[4], bfm[4];
#pragma unroll
        for (int i = 0; i < 4; ++i)
            af[i] = *(const bf16x8*)&As[(wm * 64 + i * 16 + r16) * 32 + fsw];
#pragma unroll
        for (int j = 0; j < 4; ++j)
            bfm[j] = *(const bf16x8*)&Bs[(wn * 64 + j * 16 + r16) * 32 + fsw];
#pragma unroll
        for (int i = 0; i < 4; ++i)
#pragma unroll
            for (int j = 0; j < 4; ++j)
                acc[i][j] = MFMA16(af[i], bfm[j], acc[i][j]);
    }

    // ---- epilogue: two m-half passes through Cs[128][136] ----
    const int b = m0 >> 11;            // block-uniform batch index
#pragma unroll
    for (int pass = 0; pass < 2; ++pass) {
        __syncthreads();               // K-loop / prev-pass readers done
        const bool active = ((wm >> 1) == pass);   // waves 2p, 2p+1
        const int  mhw    = wm & 1;                // wave's half-local 64-row blk
        if (z == 2) {
            if (active) {
                // Cs[nl][ml] transposed: lane's 4 r-values m-contiguous.
#pragma unroll
                for (int i = 0; i < 4; ++i) {
                    const int mbl = mhw * 64 + i * 16 + quad * 4;   // 0..127
#pragma unroll
                    for (int j = 0; j < 4; ++j) {
                        const int nl = wn * 64 + j * 16 + r16;      // 0..127
                        const float bb = bias[(n0 + nl) & 1023];
                        bf16x4 p4;
#pragma unroll
                        for (int r = 0; r < 4; ++r)
                            p4[r] = (__bf16)(acc[i][j][r] + bb);
                        *(bf16x4*)&Cs[nl * 136 + mbl] = p4;
                    }
                }
            }
            __syncthreads();
            // copy out: rows = d (nl), cols = s-contiguous (ml). 2048 chunks.
#pragma unroll
            for (int k = 0; k < 4; ++k) {
                const int id  = t + 512 * k;
                const int nll = id >> 4;                 // 0..127
                const int ml  = (id & 15) * 8;
                bf16x8 rowv = *(const bf16x8*)&Cs[nll * 136 + ml];
                const int f = (n0 + nll) & 1023, h = f >> 6, d = f & 63;
                const int s = (m0 & 2047) + pass * 128 + ml;
                *(bf16x8*)&Vt[((size_t)((b * 16 + h) * 64 + d) << 11) + s] = rowv;
            }
        } else {
            if (active) {
                // Cs[ml][nl] natural: 2B LDS writes (off the VMEM path).
#pragma unroll
                for (int i = 0; i < 4; ++i) {
                    const int mbl = mhw * 64 + i * 16 + quad * 4;   // 0..127
#pragma unroll
                    for (int j = 0; j < 4; ++j) {
                        const int nl = wn * 64 + j * 16 + r16;
                        const float bb = bias[(n0 + nl) & 1023];
#pragma unroll
                        for (int r = 0; r < 4; ++r)
                            Cs[(mbl + r) * 136 + nl] =
                                (__bf16)((acc[i][j][r] + bb) * scale);
                    }
                }
            }
            __syncthreads();
            // copy out: rows = s (ml), cols = d-contiguous (nl). 2048 chunks.
#pragma unroll
            for (int k = 0; k < 4; ++k) {
                const int id  = t + 512 * k;
                const int mll = id >> 4;                 // 0..127
                const int nl  = (id & 15) * 8;
                bf16x8 rowv = *(const bf16x8*)&Cs[mll * 136 + nl];
                const int f = (n0 + nl) & 1023, h = f >> 6, d = f & 63;
                const int s = (m0 & 2047) + pass * 128 + mll;
                *(bf16x8*)&outQK[((size_t)(b * 16 + h) << 17) + ((size_t)s << 6) + d]
                    = rowv;
            }
        }
    }
}

// ---------------------------------------------------------------------------
// Output GEMM — round-14 version (transposed grid (64,8), BK=64 + 8-chunk
// XOR swizzle, fp32 direct-store epilogue). Unchanged.
// ---------------------------------------------------------------------------
__global__ __launch_bounds__(256)
void out_gemm_kernel(const __bf16* __restrict__ A, const __bf16* __restrict__ Wob,
                     const float* __restrict__ bo, float* __restrict__ out)
{
    __shared__ __align__(16) __bf16 As[128 * 64];
    __shared__ __align__(16) __bf16 Bs[128 * 64];

    const int t    = threadIdx.x;
    const int w    = t >> 6, l = t & 63, quad = l >> 4, r16 = l & 15;
    const int wm   = w & 1, wn = w >> 1;
    const int m0   = blockIdx.x * 128;    // transposed: x = m-tile (64)
    const int n0   = blockIdx.y * 128;    //             y = n-tile (8)

    floatx4 acc[4][4];
#pragma unroll
    for (int i = 0; i < 4; ++i)
#pragma unroll
        for (int j = 0; j < 4; ++j) acc[i][j] = (floatx4){0.f, 0.f, 0.f, 0.f};

    unsigned int* lAs = (unsigned int*)As;
    unsigned int* lBs = (unsigned int*)Bs;

    const int r0 = t >> 3;
    const __bf16* Agp[4];
    const __bf16* Bgp[4];
#pragma unroll
    for (int i = 0; i < 4; ++i) {
        const int row = r0 + i * 32;
        const int sch8 = ((t & 7) ^ (row & 7)) * 8;
        Agp[i] = A   + (size_t)(m0 + row) * 1024 + sch8;
        Bgp[i] = Wob + (size_t)(n0 + row) * 1024 + sch8;
    }
    const int fsw0 = ((0 * 4 + quad) ^ (r16 & 7)) * 8;
    const int fsw1 = ((1 * 4 + quad) ^ (r16 & 7)) * 8;

    for (int k0 = 0; k0 < 1024; k0 += 64) {
        __syncthreads();
#pragma unroll
        for (int i = 0; i < 4; ++i) {
            const int c = t + 256 * i;
            GLOAD_LDS16(Agp[i] + k0, lAs + c * 4);
            GLOAD_LDS16(Bgp[i] + k0, lBs + c * 4);
        }
        __syncthreads();

#pragma unroll
        for (int kk = 0; kk < 2; ++kk) {
            const int fsw = (kk == 0) ? fsw0 : fsw1;
            bf16x8 af[4], bfm[4];
#pragma unroll
            for (int i = 0; i < 4; ++i)
                af[i] = *(const bf16x8*)&As[(wm * 64 + i * 16 + r16) * 64 + fsw];
#pragma unroll
            for (int j = 0; j < 4; ++j)
                bfm[j] = *(const bf16x8*)&Bs[(wn * 64 + j * 16 + r16) * 64 + fsw];
#pragma unroll
            for (int i = 0; i < 4; ++i)
#pragma unroll
                for (int j = 0; j < 4; ++j)
                    acc[i][j] = MFMA16(af[i], bfm[j], acc[i][j]);
        }
    }

#pragma unroll
    for (int i = 0; i < 4; ++i) {
        const int mg = m0 + wm * 64 + i * 16 + quad * 4;
#pragma unroll
        for (int j = 0; j < 4; ++j) {
            const int ng = n0 + wn * 64 + j * 16 + r16;
            const float bb = bo[ng];
#pragma unroll
            for (int r = 0; r < 4; ++r)
                out[(size_t)(mg + r) * 1024 + ng] = acc[i][j][r] + bb;
        }
    }
}

// ---------------------------------------------------------------------------
// Flash attention v10 (round-7 version, unchanged). Q pre-scaled by log2e/8,
// K in [B,H,S,64]; V^T [B,H,64,S]. 4 blocks/CU, 1-deep named-reg prefetch.
// ---------------------------------------------------------------------------
__global__ __launch_bounds__(256, 4)
void attn_kernel(const __bf16* __restrict__ Qg, const __bf16* __restrict__ Kg,
                 const __bf16* __restrict__ Vtg, __bf16* __restrict__ O)
{
    __shared__ __align__(16) __bf16 Ks[2][64 * 72];
    __shared__ __align__(16) __bf16 Vs[2][64 * 72];

    const int t    = threadIdx.x;
    const int w    = t >> 6, l = t & 63, quad = l >> 4, r16 = l & 15;
    const int bh   = blockIdx.x;
    const int y    = blockIdx.y;          // 0..15
    const int p    = y >> 1, half = y & 1;
    const int qa   = 15 - p, qb = p;
    const size_t base = (size_t)bh * SEQ * DKH;
    const int d0   = 2 * qa + half;       // block-uniform diagonal k-tile (mi=0)
    const int d1   = 2 * qb + half;       // block-uniform diagonal k-tile (mi=1)
    const int nkt  = d0 + 1;              // >= 17
    const int row0 = qa * 128 + half * 64 + w * 16;
    const int row1 = qb * 128 + half * 64 + w * 16;

    // all-ones bf16 B-fragment (1.0 = 0x3F80) for the row-sum MFMA
    const s16x4 ones16 = {(short)0x3F80, (short)0x3F80,
                          (short)0x3F80, (short)0x3F80};

    bf16x8 qf00, qf01, qf10, qf11;
    qf00 = *(const bf16x8*)&Qg[base + (size_t)(row0 + r16) * 64 + quad * 8];
    qf01 = *(const bf16x8*)&Qg[base + (size_t)(row0 + r16) * 64 + 32 + quad * 8];
    qf10 = *(const bf16x8*)&Qg[base + (size_t)(row1 + r16) * 64 + quad * 8];
    qf11 = *(const bf16x8*)&Qg[base + (size_t)(row1 + r16) * 64 + 32 + quad * 8];

    floatx4 o[2][4];
#pragma unroll
    for (int mi = 0; mi < 2; ++mi)
#pragma unroll
        for (int j = 0; j < 4; ++j) o[mi][j] = (floatx4){0.f, 0.f, 0.f, 0.f};
    floatx4 osum[2];
    osum[0] = (floatx4){0.f, 0.f, 0.f, 0.f};
    osum[1] = (floatx4){0.f, 0.f, 0.f, 0.f};

    const int srow = t >> 3;              // 0..31
    const int sg   = (t & 7) * 8;         // 0..56

    // 1-deep prefetch in NAMED registers.
    bf16x8 kc0, kc1, vc0, vc1;
    kc0 = *(const bf16x8*)&Kg[base + (size_t)srow * 64 + sg];
    kc1 = *(const bf16x8*)&Kg[base + (size_t)(32 + srow) * 64 + sg];
    vc0 = *(const bf16x8*)&Vtg[base + (size_t)srow * 2048 + sg];
    vc1 = *(const bf16x8*)&Vtg[base + (size_t)(32 + srow) * 2048 + sg];

    for (int kt = 0; kt < nkt; ++kt) {
        __bf16* ks = Ks[kt & 1];
        __bf16* vs = Vs[kt & 1];
        *(bf16x8*)&ks[srow * 72 + sg] = kc0;
        *(bf16x8*)&ks[(32 + srow) * 72 + sg] = kc1;
        *(bf16x8*)&vs[srow * 72 + sg] = vc0;
        *(bf16x8*)&vs[(32 + srow) * 72 + sg] = vc1;
        if (kt + 1 < nkt) {
            const int kr = (kt + 1) * 64;
            kc0 = *(const bf16x8*)&Kg[base + (size_t)(kr + srow) * 64 + sg];
            kc1 = *(const bf16x8*)&Kg[base + (size_t)(kr + 32 + srow) * 64 + sg];
            vc0 = *(const bf16x8*)&Vtg[base + (size_t)srow * 2048 + kr + sg];
            vc1 = *(const bf16x8*)&Vtg[base + (size_t)(32 + srow) * 2048 + kr + sg];
        }
        __syncthreads();                 // staged tile visible; prev reads done

        const bool a1 = (kt <= d1);      // block-uniform
        __builtin_amdgcn_s_setprio(1);
        bf16x8 kf0, kf1;
#pragma unroll
        for (int j = 0; j < 4; ++j) {
            kf0 = *(const bf16x8*)&ks[(j * 16 + r16) * 72 + quad * 8];
            kf1 = *(const bf16x8*)&ks[(j * 16 + r16) * 72 + 32 + quad * 8];
            floatx4 z0 = (floatx4){0.f, 0.f, 0.f, 0.f};
            floatx4 z1 = (floatx4){0.f, 0.f, 0.f, 0.f};
            z0 = MFMA16(kf0, qf00, z0);
            z0 = MFMA16(kf1, qf01, z0);
            if (a1) {
                z1 = MFMA16(kf0, qf10, z1);
                z1 = MFMA16(kf1, qf11, z1);
            }
            const int kg = kt * 64 + j * 16 + quad * 4;
            bf16x4 pb0, pb1;
            if (kt < d0) {               // full tile for mi=0
#pragma unroll
                for (int r = 0; r < 4; ++r)
                    pb0[r] = (__bf16)EXP2(z0[r]);
            } else {                     // diagonal tile for mi=0
                const int qg0 = row0 + r16;
#pragma unroll
                for (int r = 0; r < 4; ++r) {
                    float pp = 0.f;
                    if (kg + r <= qg0) pp = EXP2(z0[r]);
                    pb0[r] = (__bf16)pp;
                }
            }
            s16x4 pa0 = __builtin_bit_cast(s16x4, pb0);
            s16x4 pa1;
            if (a1) {
                if (kt < d1) {           // full tile for mi=1
#pragma unroll
                    for (int r = 0; r < 4; ++r)
                        pb1[r] = (__bf16)EXP2(z1[r]);
                } else {                 // diagonal tile for mi=1
                    const int qg1 = row1 + r16;
#pragma unroll
                    for (int r = 0; r < 4; ++r) {
                        float pp = 0.f;
                        if (kg + r <= qg1) pp = EXP2(z1[r]);
                        pb1[r] = (__bf16)pp;
                    }
                }
                pa1 = __builtin_bit_cast(s16x4, pb1);
            }
            // row-sum on the MFMA pipe (B = all-ones fragment)
            osum[0] = pv_mfma(pa0, ones16, osum[0]);
            if (a1) osum[1] = pv_mfma(pa1, ones16, osum[1]);
#pragma unroll
            for (int jd = 0; jd < 4; ++jd) {
                const s16x4 vv =
                    *(const s16x4*)&vs[(jd * 16 + r16) * 72 + j * 16 + quad * 4];
                o[0][jd] = pv_mfma(pa0, vv, o[0][jd]);
                if (a1) o[1][jd] = pv_mfma(pa1, vv, o[1][jd]);
            }
        }
        __builtin_amdgcn_s_setprio(0);
    }

    const int b = bh >> 4, h = bh & 15;
#pragma unroll
    for (int mi = 0; mi < 2; ++mi) {
        const int rowb = (mi == 0) ? row0 : row1;
#pragma unroll
        for (int r = 0; r < 4; ++r) {
            const int qrow = rowb + quad * 4 + r;
            const float inv = 1.f / osum[mi][r];   // lane-uniform along r16
#pragma unroll
            for (int jd = 0; jd < 4; ++jd) {
                const int d = jd * 16 + r16;
                O[((size_t)(b * SEQ + qrow) * D_MODEL) + h * 64 + d] =
                    (__bf16)(o[mi][jd][r] * inv);
            }
        }
    }
}

// ---------------------------------------------------------------------------
extern "C" void kernel_launch(void* const* d_in, const int* in_sizes, int n_in,
                              void* d_out, int out_size, void* d_ws, size_t ws_size,
                              hipStream_t stream)
{
    (void)in_sizes; (void)n_in; (void)out_size; (void)ws_size;
    const float* x  = (const float*)d_in[0];
    const float* Wq = (const float*)d_in[1];
    const float* bq = (const float*)d_in[2];
    const float* Wk = (const float*)d_in[3];
    const float* bk = (const float*)d_in[4];
    const float* Wv = (const float*)d_in[5];
    const float* bv = (const float*)d_in[6];
    const float* Wo = (const float*)d_in[7];
    const float* bo = (const float*)d_in[8];
    float* out = (float*)d_out;

    const size_t n_elem = (size_t)MTOT * D_MODEL;       // 8388608
    const int    w_n    = D_MODEL * D_MODEL;            // 1048576
    // d_out (33.55MB) as scratch until final GEMM: [Qb bf16][xb bf16].
    __bf16* Qb  = (__bf16*)d_out;
    __bf16* xb  = Qb + n_elem;
    // ws: [K][V^T][Ab]. Wcat overlays Ab (consumed before attn writes Ab);
    // Wob overlays dead-after-attn K.
    __bf16* Kb   = (__bf16*)d_ws;
    __bf16* Vtb  = Kb + n_elem;
    __bf16* Ab   = Vtb + n_elem;
    __bf16* Wcat = Ab;
    __bf16* Wob  = Kb;

    cvt_x_kernel<<<MTOT * D_MODEL / 1024, 256, 0, stream>>>(x, xb);
    cvt_w3_kernel<<<dim3(w_n / 1024, 3), 256, 0, stream>>>(Wq, Wk, Wv, Wcat);
    qkv_gemm_kernel<<<dim3(24, 32), 512, 0, stream>>>(xb, Wcat, bq, bk, bv,
                                                      Qb, Kb, Vtb);
    attn_kernel<<<dim3(64, 16), 256, 0, stream>>>(Qb, Kb, Vtb, Ab);
    cvt_x_kernel<<<w_n / 1024, 256, 0, stream>>>(Wo, Wob);
    out_gemm_kernel<<<dim3(64, 8), 256, 0, stream>>>(Ab, Wob, bo, out);
}

// Round 16
// 244.267 us; speedup vs baseline: 1.0423x; 1.0423x over previous
//
#include <hip/hip_runtime.h>
#include <hip/hip_bf16.h>
#include <stdint.h>

// ---- problem constants ----
#define D_MODEL 1024
#define SEQ     2048
#define BATCH   4
#define NHEAD   16
#define DKH     64
#define MTOT    (BATCH * SEQ)      // 8192

typedef __bf16 bf16x8 __attribute__((ext_vector_type(8)));
typedef __bf16 bf16x4 __attribute__((ext_vector_type(4)));
typedef float  floatx4 __attribute__((ext_vector_type(4)));
typedef short  s16x4  __attribute__((ext_vector_type(4)));

#define GLOAD_LDS16(gp, lp)                                            \
    __builtin_amdgcn_global_load_lds(                                  \
        (const __attribute__((address_space(1))) unsigned int*)(gp),   \
        (__attribute__((address_space(3))) unsigned int*)(lp), 16, 0, 0)

#define MFMA16(a, b, c) __builtin_amdgcn_mfma_f32_16x16x32_bf16(a, b, c, 0, 0, 0)

#if __has_builtin(__builtin_amdgcn_exp2f)
#define EXP2(x) __builtin_amdgcn_exp2f(x)
#else
#define EXP2(x) exp2f(x)
#endif

// PV matmul: K=16 MFMA whose A-fragment layout (A[row=l&15][k=(l>>4)*4+i])
// exactly matches the QK^T output register layout (P[q=r16][k=quad*4+r]).
static __device__ __forceinline__ floatx4 pv_mfma(s16x4 a, s16x4 b, floatx4 c)
{
#if __has_builtin(__builtin_amdgcn_mfma_f32_16x16x16bf16_1k)
    return __builtin_amdgcn_mfma_f32_16x16x16bf16_1k(a, b, c, 0, 0, 0);
#else
    asm("v_mfma_f32_16x16x16_bf16 %0, %1, %2, %0" : "+v"(c) : "v"(a), "v"(b));
    return c;
#endif
}

// ---------------------------------------------------------------------------
// fp32 -> bf16: x / Wo (exact-size grid, no guard).
// ---------------------------------------------------------------------------
__global__ __launch_bounds__(256)
void cvt_x_kernel(const float* __restrict__ src, __bf16* __restrict__ dst)
{
    const int i = (blockIdx.x * 256 + threadIdx.x) * 4;
    floatx4 v = *(const floatx4*)(src + i);
    bf16x4 o;
    o[0] = (__bf16)v[0]; o[1] = (__bf16)v[1]; o[2] = (__bf16)v[2]; o[3] = (__bf16)v[3];
    *(bf16x4*)(dst + i) = o;
}

// fp32 -> bf16: Wq/Wk/Wv stacked into Wcat[3072,1024]. grid (1024, 3).
__global__ __launch_bounds__(256)
void cvt_w3_kernel(const float* __restrict__ Wq, const float* __restrict__ Wk,
                   const float* __restrict__ Wv, __bf16* __restrict__ Wcat)
{
    const int z = blockIdx.y;
    const float* src = (z == 0) ? Wq : ((z == 1) ? Wk : Wv);
    const int i = (blockIdx.x * 256 + threadIdx.x) * 4;
    floatx4 v = *(const floatx4*)(src + i);
    bf16x4 o;
    o[0] = (__bf16)v[0]; o[1] = (__bf16)v[1]; o[2] = (__bf16)v[2]; o[3] = (__bf16)v[3];
    *(bf16x4*)(Wcat + (size_t)z * (D_MODEL * D_MODEL) + i) = o;
}

// ---------------------------------------------------------------------------
// QKV GEMM — round-7 version (best measured across 5 structural variants:
// 71.4us, VGPR 76). M=8192, N=3072, K=1024; grid (24, 64). 128x128 tile,
// BK=32, 4 waves. The 1.5-scheduling-round tail at 4 blocks/CU is the
// residual limit and proved irreducible (rounds 8-11, 15).
// z = n0>>10: 0->Q [b,h,s,d] (PRE-SCALED by log2e/8), 1->K, 2->V^T [b,h,d,s].
// ---------------------------------------------------------------------------
__global__ __launch_bounds__(256)
void qkv_gemm_kernel(const __bf16* __restrict__ xb, const __bf16* __restrict__ Wcat,
                     const float* __restrict__ bq, const float* __restrict__ bk,
                     const float* __restrict__ bv,
                     __bf16* __restrict__ Q, __bf16* __restrict__ K,
                     __bf16* __restrict__ Vt)
{
    // As/Bs (128x32 each) live during the K-loop; Cs (128x136) reuses the
    // whole allocation for the epilogue re-layout.
    __shared__ __align__(16) char smem_raw[128 * 136 * 2];
    __bf16* As = (__bf16*)smem_raw;
    __bf16* Bs = (__bf16*)(smem_raw + 8192);
    __bf16* Cs = (__bf16*)smem_raw;

    const int t    = threadIdx.x;
    const int w    = t >> 6, l = t & 63, quad = l >> 4, r16 = l & 15;
    const int wm   = w & 1, wn = w >> 1;
    const int m0   = blockIdx.y * 128;
    const int n0   = blockIdx.x * 128;
    const int z    = n0 >> 10;                        // block-uniform
    const float* bias = (z == 0) ? bq : ((z == 1) ? bk : bv);
    __bf16* outQK     = (z == 0) ? Q  : K;
    // fold 1/sqrt(64) * log2(e) into Q so attention can use raw v_exp_f32
    const float scale = (z == 0) ? 0.18033688011112042f : 1.0f;

    floatx4 acc[4][4];
#pragma unroll
    for (int i = 0; i < 4; ++i)
#pragma unroll
        for (int j = 0; j < 4; ++j) acc[i][j] = (floatx4){0.f, 0.f, 0.f, 0.f};

    // staging addresses (source chunk pre-swizzled; LDS dest linear)
    const int c0 = t, c1 = t + 256;
    const int row0 = c0 >> 2, s0 = ((c0 & 3) ^ (row0 & 3)) * 8;
    const int row1 = c1 >> 2, s1 = ((c1 & 3) ^ (row1 & 3)) * 8;
    const __bf16* Ag0 = xb   + (size_t)(m0 + row0) * 1024 + s0;
    const __bf16* Ag1 = xb   + (size_t)(m0 + row1) * 1024 + s1;
    const __bf16* Bg0 = Wcat + (size_t)(n0 + row0) * 1024 + s0;
    const __bf16* Bg1 = Wcat + (size_t)(n0 + row1) * 1024 + s1;
    unsigned int* lAs = (unsigned int*)As;
    unsigned int* lBs = (unsigned int*)Bs;

    // fragment read swizzle: chunk' = quad ^ (r16&3)
    const int fsw = (quad ^ (r16 & 3)) * 8;

    for (int k0 = 0; k0 < 1024; k0 += 32) {
        __syncthreads();
        GLOAD_LDS16(Ag0 + k0, lAs + c0 * 4);
        GLOAD_LDS16(Ag1 + k0, lAs + c1 * 4);
        GLOAD_LDS16(Bg0 + k0, lBs + c0 * 4);
        GLOAD_LDS16(Bg1 + k0, lBs + c1 * 4);
        __syncthreads();

        bf16x8 af[4], bfm[4];
#pragma unroll
        for (int i = 0; i < 4; ++i)
            af[i] = *(const bf16x8*)&As[(wm * 64 + i * 16 + r16) * 32 + fsw];
#pragma unroll
        for (int j = 0; j < 4; ++j)
            bfm[j] = *(const bf16x8*)&Bs[(wn * 64 + j * 16 + r16) * 32 + fsw];
#pragma unroll
        for (int i = 0; i < 4; ++i)
#pragma unroll
            for (int j = 0; j < 4; ++j)
                acc[i][j] = MFMA16(af[i], bfm[j], acc[i][j]);
    }

    // ---- epilogue: LDS re-layout, then coalesced bf16x8 stores ----
    __syncthreads();            // all waves done reading As/Bs

    if (z == 2) {
        // Cs[n_local][m_local] (transposed): lane's 4 r-values m-contiguous.
#pragma unroll
        for (int i = 0; i < 4; ++i) {
            const int mb = wm * 64 + i * 16 + quad * 4;
#pragma unroll
            for (int j = 0; j < 4; ++j) {
                const int nl = wn * 64 + j * 16 + r16;
                const float bb = bias[(n0 + nl) & 1023];
                bf16x4 p4;
#pragma unroll
                for (int r = 0; r < 4; ++r) p4[r] = (__bf16)(acc[i][j][r] + bb);
                *(bf16x4*)&Cs[nl * 136 + mb] = p4;
            }
        }
    } else {
        // Cs[m_local][n_local] (natural): 2B LDS writes (off the VMEM path).
#pragma unroll
        for (int i = 0; i < 4; ++i) {
            const int mb = wm * 64 + i * 16 + quad * 4;
#pragma unroll
            for (int j = 0; j < 4; ++j) {
                const int nl = wn * 64 + j * 16 + r16;
                const float bb = bias[(n0 + nl) & 1023];
#pragma unroll
                for (int r = 0; r < 4; ++r)
                    Cs[(mb + r) * 136 + nl] =
                        (__bf16)((acc[i][j][r] + bb) * scale);
            }
        }
    }
    __syncthreads();

    const int b  = m0 >> 11;           // block-uniform batch index
    if (z == 2) {
        // rows of Cs = V^T rows (d); cols = s contiguous -> 256B runs.
#pragma unroll
        for (int k = 0; k < 8; ++k) {
            const int nl = (t >> 4) + k * 16;
            const int ml = (t & 15) * 8;
            bf16x8 row = *(const bf16x8*)&Cs[nl * 136 + ml];
            const int f = (n0 + nl) & 1023, h = f >> 6, d = f & 63;
            const int s = (m0 & 2047) + ml;
            *(bf16x8*)&Vt[((size_t)((b * 16 + h) * 64 + d) << 11) + s] = row;
        }
    } else {
        // rows of Cs = m (s); cols = n -> d contiguous within a head.
#pragma unroll
        for (int k = 0; k < 8; ++k) {
            const int ml = (t >> 4) + k * 16;
            const int nl = (t & 15) * 8;
            bf16x8 row = *(const bf16x8*)&Cs[ml * 136 + nl];
            const int f = (n0 + nl) & 1023, h = f >> 6, d = f & 63;
            const int s = (m0 & 2047) + ml;
            *(bf16x8*)&outQK[((size_t)(b * 16 + h) << 17) + ((size_t)s << 6) + d]
                = row;
        }
    }
}

// ---------------------------------------------------------------------------
// Output GEMM — round-14 version: transposed grid (64, 8) so A-panel sharers
// land on one XCD (bid = x mod 8); BK=64 + 8-chunk XOR swizzle; fp32
// direct-store epilogue.
// ---------------------------------------------------------------------------
__global__ __launch_bounds__(256)
void out_gemm_kernel(const __bf16* __restrict__ A, const __bf16* __restrict__ Wob,
                     const float* __restrict__ bo, float* __restrict__ out)
{
    __shared__ __align__(16) __bf16 As[128 * 64];
    __shared__ __align__(16) __bf16 Bs[128 * 64];

    const int t    = threadIdx.x;
    const int w    = t >> 6, l = t & 63, quad = l >> 4, r16 = l & 15;
    const int wm   = w & 1, wn = w >> 1;
    const int m0   = blockIdx.x * 128;    // transposed: x = m-tile (64)
    const int n0   = blockIdx.y * 128;    //             y = n-tile (8)

    floatx4 acc[4][4];
#pragma unroll
    for (int i = 0; i < 4; ++i)
#pragma unroll
        for (int j = 0; j < 4; ++j) acc[i][j] = (floatx4){0.f, 0.f, 0.f, 0.f};

    unsigned int* lAs = (unsigned int*)As;
    unsigned int* lBs = (unsigned int*)Bs;

    const int r0 = t >> 3;
    const __bf16* Agp[4];
    const __bf16* Bgp[4];
#pragma unroll
    for (int i = 0; i < 4; ++i) {
        const int row = r0 + i * 32;
        const int sch8 = ((t & 7) ^ (row & 7)) * 8;
        Agp[i] = A   + (size_t)(m0 + row) * 1024 + sch8;
        Bgp[i] = Wob + (size_t)(n0 + row) * 1024 + sch8;
    }
    const int fsw0 = ((0 * 4 + quad) ^ (r16 & 7)) * 8;
    const int fsw1 = ((1 * 4 + quad) ^ (r16 & 7)) * 8;

    for (int k0 = 0; k0 < 1024; k0 += 64) {
        __syncthreads();
#pragma unroll
        for (int i = 0; i < 4; ++i) {
            const int c = t + 256 * i;
            GLOAD_LDS16(Agp[i] + k0, lAs + c * 4);
            GLOAD_LDS16(Bgp[i] + k0, lBs + c * 4);
        }
        __syncthreads();

#pragma unroll
        for (int kk = 0; kk < 2; ++kk) {
            const int fsw = (kk == 0) ? fsw0 : fsw1;
            bf16x8 af[4], bfm[4];
#pragma unroll
            for (int i = 0; i < 4; ++i)
                af[i] = *(const bf16x8*)&As[(wm * 64 + i * 16 + r16) * 64 + fsw];
#pragma unroll
            for (int j = 0; j < 4; ++j)
                bfm[j] = *(const bf16x8*)&Bs[(wn * 64 + j * 16 + r16) * 64 + fsw];
#pragma unroll
            for (int i = 0; i < 4; ++i)
#pragma unroll
                for (int j = 0; j < 4; ++j)
                    acc[i][j] = MFMA16(af[i], bfm[j], acc[i][j]);
        }
    }

#pragma unroll
    for (int i = 0; i < 4; ++i) {
        const int mg = m0 + wm * 64 + i * 16 + quad * 4;
#pragma unroll
        for (int j = 0; j < 4; ++j) {
            const int ng = n0 + wn * 64 + j * 16 + r16;
            const float bb = bo[ng];
#pragma unroll
            for (int r = 0; r < 4; ++r)
                out[(size_t)(mg + r) * 1024 + ng] = acc[i][j][r] + bb;
        }
    }
}

// ---------------------------------------------------------------------------
// Flash attention v10 (round-7 version). Q pre-scaled by log2e/8,
// K in [B,H,S,64]; V^T [B,H,64,S]. 4 blocks/CU, 1-deep named-reg prefetch,
// P-in-registers PV, row-sum on MFMA pipe, block-uniform diagonals.
// ---------------------------------------------------------------------------
__global__ __launch_bounds__(256, 4)
void attn_kernel(const __bf16* __restrict__ Qg, const __bf16* __restrict__ Kg,
                 const __bf16* __restrict__ Vtg, __bf16* __restrict__ O)
{
    __shared__ __align__(16) __bf16 Ks[2][64 * 72];
    __shared__ __align__(16) __bf16 Vs[2][64 * 72];

    const int t    = threadIdx.x;
    const int w    = t >> 6, l = t & 63, quad = l >> 4, r16 = l & 15;
    const int bh   = blockIdx.x;
    const int y    = blockIdx.y;          // 0..15
    const int p    = y >> 1, half = y & 1;
    const int qa   = 15 - p, qb = p;
    const size_t base = (size_t)bh * SEQ * DKH;
    const int d0   = 2 * qa + half;       // block-uniform diagonal k-tile (mi=0)
    const int d1   = 2 * qb + half;       // block-uniform diagonal k-tile (mi=1)
    const int nkt  = d0 + 1;              // >= 17
    const int row0 = qa * 128 + half * 64 + w * 16;
    const int row1 = qb * 128 + half * 64 + w * 16;

    // all-ones bf16 B-fragment (1.0 = 0x3F80) for the row-sum MFMA
    const s16x4 ones16 = {(short)0x3F80, (short)0x3F80,
                          (short)0x3F80, (short)0x3F80};

    bf16x8 qf00, qf01, qf10, qf11;
    qf00 = *(const bf16x8*)&Qg[base + (size_t)(row0 + r16) * 64 + quad * 8];
    qf01 = *(const bf16x8*)&Qg[base + (size_t)(row0 + r16) * 64 + 32 + quad * 8];
    qf10 = *(const bf16x8*)&Qg[base + (size_t)(row1 + r16) * 64 + quad * 8];
    qf11 = *(const bf16x8*)&Qg[base + (size_t)(row1 + r16) * 64 + 32 + quad * 8];

    floatx4 o[2][4];
#pragma unroll
    for (int mi = 0; mi < 2; ++mi)
#pragma unroll
        for (int j = 0; j < 4; ++j) o[mi][j] = (floatx4){0.f, 0.f, 0.f, 0.f};
    floatx4 osum[2];
    osum[0] = (floatx4){0.f, 0.f, 0.f, 0.f};
    osum[1] = (floatx4){0.f, 0.f, 0.f, 0.f};

    const int srow = t >> 3;              // 0..31
    const int sg   = (t & 7) * 8;         // 0..56

    // 1-deep prefetch in NAMED registers.
    bf16x8 kc0, kc1, vc0, vc1;
    kc0 = *(const bf16x8*)&Kg[base + (size_t)srow * 64 + sg];
    kc1 = *(const bf16x8*)&Kg[base + (size_t)(32 + srow) * 64 + sg];
    vc0 = *(const bf16x8*)&Vtg[base + (size_t)srow * 2048 + sg];
    vc1 = *(const bf16x8*)&Vtg[base + (size_t)(32 + srow) * 2048 + sg];

    for (int kt = 0; kt < nkt; ++kt) {
        __bf16* ks = Ks[kt & 1];
        __bf16* vs = Vs[kt & 1];
        *(bf16x8*)&ks[srow * 72 + sg] = kc0;
        *(bf16x8*)&ks[(32 + srow) * 72 + sg] = kc1;
        *(bf16x8*)&vs[srow * 72 + sg] = vc0;
        *(bf16x8*)&vs[(32 + srow) * 72 + sg] = vc1;
        if (kt + 1 < nkt) {
            const int kr = (kt + 1) * 64;
            kc0 = *(const bf16x8*)&Kg[base + (size_t)(kr + srow) * 64 + sg];
            kc1 = *(const bf16x8*)&Kg[base + (size_t)(kr + 32 + srow) * 64 + sg];
            vc0 = *(const bf16x8*)&Vtg[base + (size_t)srow * 2048 + kr + sg];
            vc1 = *(const bf16x8*)&Vtg[base + (size_t)(32 + srow) * 2048 + kr + sg];
        }
        __syncthreads();                 // staged tile visible; prev reads done

        const bool a1 = (kt <= d1);      // block-uniform
        __builtin_amdgcn_s_setprio(1);
        bf16x8 kf0, kf1;
#pragma unroll
        for (int j = 0; j < 4; ++j) {
            kf0 = *(const bf16x8*)&ks[(j * 16 + r16) * 72 + quad * 8];
            kf1 = *(const bf16x8*)&ks[(j * 16 + r16) * 72 + 32 + quad * 8];
            floatx4 z0 = (floatx4){0.f, 0.f, 0.f, 0.f};
            floatx4 z1 = (floatx4){0.f, 0.f, 0.f, 0.f};
            z0 = MFMA16(kf0, qf00, z0);
            z0 = MFMA16(kf1, qf01, z0);
            if (a1) {
                z1 = MFMA16(kf0, qf10, z1);
                z1 = MFMA16(kf1, qf11, z1);
            }
            const int kg = kt * 64 + j * 16 + quad * 4;
            bf16x4 pb0, pb1;
            if (kt < d0) {               // full tile for mi=0
#pragma unroll
                for (int r = 0; r < 4; ++r)
                    pb0[r] = (__bf16)EXP2(z0[r]);
            } else {                     // diagonal tile for mi=0
                const int qg0 = row0 + r16;
#pragma unroll
                for (int r = 0; r < 4; ++r) {
                    float pp = 0.f;
                    if (kg + r <= qg0) pp = EXP2(z0[r]);
                    pb0[r] = (__bf16)pp;
                }
            }
            s16x4 pa0 = __builtin_bit_cast(s16x4, pb0);
            s16x4 pa1;
            if (a1) {
                if (kt < d1) {           // full tile for mi=1
#pragma unroll
                    for (int r = 0; r < 4; ++r)
                        pb1[r] = (__bf16)EXP2(z1[r]);
                } else {                 // diagonal tile for mi=1
                    const int qg1 = row1 + r16;
#pragma unroll
                    for (int r = 0; r < 4; ++r) {
                        float pp = 0.f;
                        if (kg + r <= qg1) pp = EXP2(z1[r]);
                        pb1[r] = (__bf16)pp;
                    }
                }
                pa1 = __builtin_bit_cast(s16x4, pb1);
            }
            // row-sum on the MFMA pipe (B = all-ones fragment)
            osum[0] = pv_mfma(pa0, ones16, osum[0]);
            if (a1) osum[1] = pv_mfma(pa1, ones16, osum[1]);
#pragma unroll
            for (int jd = 0; jd < 4; ++jd) {
                const s16x4 vv =
                    *(const s16x4*)&vs[(jd * 16 + r16) * 72 + j * 16 + quad * 4];
                o[0][jd] = pv_mfma(pa0, vv, o[0][jd]);
                if (a1) o[1][jd] = pv_mfma(pa1, vv, o[1][jd]);
            }
        }
        __builtin_amdgcn_s_setprio(0);
    }

    const int b = bh >> 4, h = bh & 15;
#pragma unroll
    for (int mi = 0; mi < 2; ++mi) {
        const int rowb = (mi == 0) ? row0 : row1;
#pragma unroll
        for (int r = 0; r < 4; ++r) {
            const int qrow = rowb + quad * 4 + r;
            const float inv = 1.f / osum[mi][r];   // lane-uniform along r16
#pragma unroll
            for (int jd = 0; jd < 4; ++jd) {
                const int d = jd * 16 + r16;
                O[((size_t)(b * SEQ + qrow) * D_MODEL) + h * 64 + d] =
                    (__bf16)(o[mi][jd][r] * inv);
            }
        }
    }
}

// ---------------------------------------------------------------------------
extern "C" void kernel_launch(void* const* d_in, const int* in_sizes, int n_in,
                              void* d_out, int out_size, void* d_ws, size_t ws_size,
                              hipStream_t stream)
{
    (void)in_sizes; (void)n_in; (void)out_size; (void)ws_size;
    const float* x  = (const float*)d_in[0];
    const float* Wq = (const float*)d_in[1];
    const float* bq = (const float*)d_in[2];
    const float* Wk = (const float*)d_in[3];
    const float* bk = (const float*)d_in[4];
    const float* Wv = (const float*)d_in[5];
    const float* bv = (const float*)d_in[6];
    const float* Wo = (const float*)d_in[7];
    const float* bo = (const float*)d_in[8];
    float* out = (float*)d_out;

    const size_t n_elem = (size_t)MTOT * D_MODEL;       // 8388608
    const int    w_n    = D_MODEL * D_MODEL;            // 1048576
    // d_out (33.55MB) as scratch until final GEMM: [Qb bf16][xb bf16].
    __bf16* Qb  = (__bf16*)d_out;
    __bf16* xb  = Qb + n_elem;
    // ws: [K][V^T][Ab]. Wcat overlays Ab (consumed before attn writes Ab);
    // Wob overlays dead-after-attn K.
    __bf16* Kb   = (__bf16*)d_ws;
    __bf16* Vtb  = Kb + n_elem;
    __bf16* Ab   = Vtb + n_elem;
    __bf16* Wcat = Ab;
    __bf16* Wob  = Kb;

    cvt_x_kernel<<<MTOT * D_MODEL / 1024, 256, 0, stream>>>(x, xb);
    cvt_w3_kernel<<<dim3(w_n / 1024, 3), 256, 0, stream>>>(Wq, Wk, Wv, Wcat);
    qkv_gemm_kernel<<<dim3(24, 64), 256, 0, stream>>>(xb, Wcat, bq, bk, bv,
                                                      Qb, Kb, Vtb);
    attn_kernel<<<dim3(64, 16), 256, 0, stream>>>(Qb, Kb, Vtb, Ab);
    cvt_x_kernel<<<w_n / 1024, 256, 0, stream>>>(Wo, Wob);
    out_gemm_kernel<<<dim3(64, 8), 256, 0, stream>>>(Ab, Wob, bo, out);
}